// Round 4
// baseline (343.074 us; speedup 1.0000x reference)
//
#include <hip/hip_runtime.h>
#include <hip/hip_cooperative_groups.h>
#include <math.h>

namespace cg = cooperative_groups;

// ---------------------------------------------------------------------------
// MMoE feed-forward: single persistent cooperative kernel.
// Phases (grid.sync between): xp -> gate -> wtrans+prep -> conv1 -> conv2 ->
// combine. bf16 NHWC MFMA implicit-GEMM convs, frag-ordered weight stream.
//
// ws layout (elements):
//   wsf (f32) [0..1023]: wsi[0..7]=slot expert, wsi[8..15]=slot batch,
//                        wsf[16..23]=gate
//   wt2 (bf16)  8 * 294912   per-slot weights, MFMA-frag order:
//               [which][k=tap*4+icc][oc16blk(0..7)][lane(0..63)][j(0..7)]
//   buf0 (bf16) 8 * 524288   NHWC slot buffers
//   buf1 (bf16) 8 * 524288
// ---------------------------------------------------------------------------

typedef __attribute__((ext_vector_type(8))) short bf16x8;
typedef __attribute__((ext_vector_type(4))) float f32x4;

#define SLOT_ELEMS 524288            // 128*64*64
#define WT_ELEMS   294912            // 2*9*128*128

__device__ inline ushort f2bf(float f) {
  unsigned u = __float_as_uint(f);
  return (ushort)((u + 0x7FFFu + ((u >> 16) & 1u)) >> 16);
}
__device__ inline float bf2f(ushort h) {
  return __uint_as_float(((unsigned)h) << 16);
}

union SharedU {
  ushort sIn[100 * 136];             // conv input tile+halo: 27.2 KB (max)
  ushort sT[128 * 65];               // prep transpose: 16.6 KB
  float  sO[32 * 129];               // combine transpose: 16.5 KB
  float  red4[4];                    // xp reduce
  struct {
    float part[4][64];
    float slog[64], sprob[64], ssum[4];
  } g;                               // gate
};

// ---------------- conv phase (device function) ------------------------------
__device__ __forceinline__ void conv_phase(const int* wsi,
                                           const ushort* __restrict__ bufin,
                                           ushort* __restrict__ bufout,
                                           const ushort* __restrict__ wt,
                                           int which,
                                           const float* __restrict__ ball,
                                           int gelu, SharedU& sh,
                                           int bid, int tid) {
  int slot = bid & 7;                // slot fastest -> per-slot XCD affinity
  int tile = bid >> 3;
  int e = wsi[slot];
  int tp = e % 3;
  int S = (tp == 0) ? 32 : ((tp == 1) ? 64 : 16);
  int tpr = S >> 3;
  if (tile >= tpr * tpr) return;
  int tr = (tile / tpr) << 3;
  int tc = (tile % tpr) << 3;

  const ushort* in = bufin + (size_t)slot * SLOT_ELEMS;

  // stage input tile + halo (all 128 ch), zero 'SAME' padding
  for (int u = tid; u < 1600; u += 256) {
    int p = u >> 4, q = u & 15;
    int hr = p / 10, wc = p - hr * 10;
    int gh = tr + hr - 1, gw = tc + wc - 1;
    bf16x8 v = {0, 0, 0, 0, 0, 0, 0, 0};
    if (gh >= 0 && gh < S && gw >= 0 && gw < S)
      v = *(const bf16x8*)&in[(size_t)(gh * S + gw) * 128 + q * 8];
    *(bf16x8*)&sh.sIn[p * 136 + q * 8] = v;
  }

  int wid = tid >> 6, lane = tid & 63;
  int ln = lane & 15, lg = lane >> 4;

  f32x4 acc[2][4];
  #pragma unroll
  for (int m = 0; m < 2; ++m)
    #pragma unroll
    for (int n = 0; n < 4; ++n)
      #pragma unroll
      for (int j = 0; j < 4; ++j) acc[m][n][j] = 0.0f;

  int pxb[4];
  #pragma unroll
  for (int n = 0; n < 4; ++n) {
    int px = n * 16 + ln;
    pxb[n] = (px >> 3) * 10 + (px & 7);
  }

  const ushort* wbase = wt + (size_t)slot * WT_ELEMS + (size_t)which * 147456
                        + (size_t)(wid * 2) * 512 + lane * 8;

  // prefetch 2 k-steps of A-frags before the barrier
  bf16x8 abuf[3][2];
  #pragma unroll
  for (int i = 0; i < 2; ++i) {
    abuf[i][0] = *(const bf16x8*)&wbase[(size_t)i * 4096];
    abuf[i][1] = *(const bf16x8*)&wbase[(size_t)i * 4096 + 512];
  }

  __syncthreads();

  #pragma unroll 6
  for (int kk = 0; kk < 36; ++kk) {          // k = tap*4 + icc
    if (kk + 2 < 36) {
      abuf[(kk + 2) % 3][0] = *(const bf16x8*)&wbase[(size_t)(kk + 2) * 4096];
      abuf[(kk + 2) % 3][1] = *(const bf16x8*)&wbase[(size_t)(kk + 2) * 4096 + 512];
    }
    int tap = kk >> 2, icc = kk & 3;
    int off = (tap / 3) * 10 + (tap % 3);
    bf16x8 bfr[4];
    #pragma unroll
    for (int n = 0; n < 4; ++n)
      bfr[n] = *(bf16x8*)&sh.sIn[(pxb[n] + off) * 136 + icc * 32 + lg * 8];
    #pragma unroll
    for (int m = 0; m < 2; ++m)
      #pragma unroll
      for (int n = 0; n < 4; ++n)
        acc[m][n] = __builtin_amdgcn_mfma_f32_16x16x32_bf16(abuf[kk % 3][m], bfr[n],
                                                            acc[m][n], 0, 0, 0);
  }

  // epilogue: bias (+gelu), pack bf16, NHWC store
  ushort* outp = bufout + (size_t)slot * SLOT_ELEMS;
  const float* bias = ball + e * 128;
  int ocw = wid << 5;
  #pragma unroll
  for (int m = 0; m < 2; ++m) {
    int oc0 = ocw + m * 16 + lg * 4;
    float bv[4];
    #pragma unroll
    for (int j = 0; j < 4; ++j) bv[j] = bias[oc0 + j];
    #pragma unroll
    for (int n = 0; n < 4; ++n) {
      int px = n * 16 + ln;
      int gh = tr + (px >> 3), gw = tc + (px & 7);
      float v0 = acc[m][n][0] + bv[0];
      float v1 = acc[m][n][1] + bv[1];
      float v2 = acc[m][n][2] + bv[2];
      float v3 = acc[m][n][3] + bv[3];
      if (gelu) {
        v0 = 0.5f * v0 * (1.0f + erff(v0 * 0.70710678118654752f));
        v1 = 0.5f * v1 * (1.0f + erff(v1 * 0.70710678118654752f));
        v2 = 0.5f * v2 * (1.0f + erff(v2 * 0.70710678118654752f));
        v3 = 0.5f * v3 * (1.0f + erff(v3 * 0.70710678118654752f));
      }
      unsigned pk0 = (unsigned)f2bf(v0) | ((unsigned)f2bf(v1) << 16);
      unsigned pk1 = (unsigned)f2bf(v2) | ((unsigned)f2bf(v3) << 16);
      uint2 st; st.x = pk0; st.y = pk1;
      *(uint2*)&outp[(size_t)(gh * S + gw) * 128 + oc0] = st;
    }
  }
}

// ---------------- the mega kernel -------------------------------------------
__global__ __launch_bounds__(256, 2) void mega_kernel(
    const float* __restrict__ x, const float* __restrict__ tf,
    const float* __restrict__ Wx, const float* __restrict__ Wt,
    const float* __restrict__ cw1, const float* __restrict__ cb1,
    const float* __restrict__ cw2, const float* __restrict__ cb2,
    float* __restrict__ out, float* __restrict__ wsf,
    ushort* __restrict__ wt2, ushort* __restrict__ buf0,
    ushort* __restrict__ buf1) {
  __shared__ SharedU sh;
  cg::grid_group grid = cg::this_grid();
  int bid = blockIdx.x;                      // 0..511
  int tid = threadIdx.x;
  const int* wsi = (const int*)wsf;

  // ==== P0: xp — per-(b,c) spatial mean (512 items, 1 per block) ====
  {
    const float4* p = (const float4*)(x + (size_t)bid * 1024);
    float4 v = p[tid];
    float s = v.x + v.y + v.z + v.w;
    #pragma unroll
    for (int off = 32; off > 0; off >>= 1) s += __shfl_down(s, off);
    if ((tid & 63) == 0) sh.red4[tid >> 6] = s;
    __syncthreads();
    if (tid == 0)
      wsf[64 + bid] = (sh.red4[0] + sh.red4[1] + sh.red4[2] + sh.red4[3]) *
                      (1.0f / 1024.0f);
  }
  grid.sync();

  // ==== P1: gate (block 0 only) ====
  if (bid == 0) {
    int p = tid >> 6, be = tid & 63;
    int b = be >> 4, e = be & 15;
    const float* xp = wsf + 64;
    float acc = 0.0f;
    for (int c = p * 32; c < p * 32 + 32; ++c) acc += xp[b * 128 + c] * Wx[c * 16 + e];
    for (int d = p * 128; d < p * 128 + 128; ++d) acc += tf[b * 512 + d] * Wt[d * 16 + e];
    sh.g.part[p][be] = acc;
    __syncthreads();
    if (tid < 64) sh.g.slog[be] = sh.g.part[0][be] + sh.g.part[1][be] +
                                  sh.g.part[2][be] + sh.g.part[3][be];
    __syncthreads();
    if (tid < 64) {
      float m = sh.g.slog[b * 16];
      for (int j = 1; j < 16; ++j) m = fmaxf(m, sh.g.slog[b * 16 + j]);
      sh.g.sprob[be] = expf(sh.g.slog[be] - m);
    }
    __syncthreads();
    if (tid < 4) {                           // tid = b
      float s = 0.0f;
      for (int j = 0; j < 16; ++j) s += sh.g.sprob[tid * 16 + j];
      sh.g.ssum[tid] = s;
      int i1 = 0; float v1 = -1.0f;
      for (int j = 0; j < 16; ++j) {
        float v = sh.g.sprob[tid * 16 + j];
        if (v > v1) { v1 = v; i1 = j; }
      }
      int i2 = -1; float v2 = -1.0f;
      for (int j = 0; j < 16; ++j) {
        if (j == i1) continue;
        float v = sh.g.sprob[tid * 16 + j];
        if (v > v2) { v2 = v; i2 = j; }
      }
      float inv = 1.0f / (v1 + v2);          // softmax denom cancels
      int* wsiw = (int*)wsf;
      wsiw[2 * tid]     = i1;  wsiw[2 * tid + 1]     = i2;
      wsiw[8 + 2 * tid] = tid; wsiw[8 + 2 * tid + 1] = tid;
      wsf[16 + 2 * tid]     = v1 * inv;
      wsf[16 + 2 * tid + 1] = v2 * inv;
    }
    __syncthreads();
    if (tid == 0) {
      float kl = 0.0f;
      for (int j = 0; j < 16; ++j) {
        float pe = 0.25f * (sh.g.sprob[j] / sh.g.ssum[0] +
                            sh.g.sprob[16 + j] / sh.g.ssum[1] +
                            sh.g.sprob[32 + j] / sh.g.ssum[2] +
                            sh.g.sprob[48 + j] / sh.g.ssum[3]);
        kl += pe * logf(pe / (pe + 1e-7f) + 1e-7f);
      }
      out[524288] = -0.01f * kl;             // mi_loss
    }
  }
  grid.sync();

  // ==== P2: wtrans (items 0..9215) + prep (items 9216..9727) ====
  for (int item = bid; item < 9728; item += 512) {
    if (item < 9216) {
      // weight transpose into MFMA-frag order
      int slot = item / 1152;
      int e = wsi[slot];
      int idx = (item - slot * 1152) * 256 + tid;   // < 294912
      int which = idx / 147456;
      int r = idx - which * 147456;
      int pos = r & 511;                      // lane*8 + j
      int chunk = r >> 9;                     // (tap*4+icc)*8 + blk
      int blk = chunk & 7;
      int t2 = chunk >> 3;
      int icc = t2 & 3, tap = t2 >> 2;
      int lane8 = pos >> 3, j = pos & 7;
      int oc = blk * 16 + (lane8 & 15);
      int ic = icc * 32 + (lane8 >> 4) * 8 + j;
      const float* src = which ? cw2 : cw1;
      wt2[(size_t)slot * WT_ELEMS + idx] =
          f2bf(src[(((size_t)e * 128 + oc) * 128 + ic) * 9 + tap]);
    } else {
      // prep: NCHW f32 (+spatial xform) -> NHWC bf16
      int pitem = item - 9216;                // 0..511
      int chunk = pitem & 63, slot = pitem >> 6;
      int e = wsi[slot];
      int b = wsi[8 + slot];
      int tp = e % 3;
      int S = (tp == 0) ? 32 : ((tp == 1) ? 64 : 16);
      if (chunk * 64 >= S * S) continue;
      const float* xb = x + (size_t)b * 131072;
      int pxl0 = tid & 63, c0 = tid >> 6;
      __syncthreads();
      #pragma unroll 4
      for (int i = 0; i < 32; ++i) {
        int c = i * 4 + c0;
        int px = chunk * 64 + pxl0;
        float v;
        if (tp == 0) {
          v = xb[c * 1024 + px];
        } else if (tp == 1) {
          int h = px >> 6, w = px & 63;
          v = xb[c * 1024 + (h >> 1) * 32 + (w >> 1)];
        } else {
          int h = px >> 4, w = px & 15;
          const float* p = xb + c * 1024 + (h << 1) * 32 + (w << 1);
          v = fmaxf(fmaxf(p[0], p[1]), fmaxf(p[32], p[33]));
        }
        sh.sT[c * 65 + pxl0] = f2bf(v);
      }
      __syncthreads();
      ushort* ob = buf0 + (size_t)slot * SLOT_ELEMS;
      #pragma unroll
      for (int i = 0; i < 4; ++i) {
        int u = i * 256 + tid;
        int pxl = u >> 4, q = u & 15;
        bf16x8 pk;
        #pragma unroll
        for (int j = 0; j < 8; ++j) pk[j] = (short)sh.sT[(q * 8 + j) * 65 + pxl];
        *(bf16x8*)&ob[(size_t)(chunk * 64 + pxl) * 128 + q * 8] = pk;
      }
    }
  }
  grid.sync();

  // ==== P3: conv1 (bias + GELU) ====
  conv_phase(wsi, buf0, buf1, wt2, 0, cb1, 1, sh, bid, tid);
  grid.sync();

  // ==== P4: conv2 (bias) ====
  conv_phase(wsi, buf1, buf0, wt2, 1, cb2, 0, sh, bid, tid);
  grid.sync();

  // ==== P5: combine — post-transform * gate, NHWC bf16 -> NCHW f32 ====
  if (bid < 128) {
    int chunk = bid & 31, b = bid >> 5;
    #pragma unroll
    for (int i = 0; i < 2; ++i) {
      int u = i * 256 + tid;
      int pxl = u >> 4, q = u & 15;
      int px = chunk * 32 + pxl;
      int h = px >> 5, w = px & 31;
      float a8[8];
      #pragma unroll
      for (int j = 0; j < 8; ++j) a8[j] = 0.0f;
      for (int s = 0; s < 2; ++s) {
        int slot = 2 * b + s;
        int e = wsi[slot];
        float g = wsf[16 + slot];
        int tp = e % 3;
        const ushort* cin = buf0 + (size_t)slot * SLOT_ELEMS;
        if (tp == 0) {
          bf16x8 v = *(const bf16x8*)&cin[(size_t)(h * 32 + w) * 128 + q * 8];
          #pragma unroll
          for (int j = 0; j < 8; ++j) a8[j] += g * bf2f((ushort)v[j]);
        } else if (tp == 1) {                 // maxpool from 64x64
          bf16x8 v00 = *(const bf16x8*)&cin[(size_t)((2*h) * 64 + 2*w) * 128 + q * 8];
          bf16x8 v01 = *(const bf16x8*)&cin[(size_t)((2*h) * 64 + 2*w + 1) * 128 + q * 8];
          bf16x8 v10 = *(const bf16x8*)&cin[(size_t)((2*h+1) * 64 + 2*w) * 128 + q * 8];
          bf16x8 v11 = *(const bf16x8*)&cin[(size_t)((2*h+1) * 64 + 2*w + 1) * 128 + q * 8];
          #pragma unroll
          for (int j = 0; j < 8; ++j) {
            float mv = fmaxf(fmaxf(bf2f((ushort)v00[j]), bf2f((ushort)v01[j])),
                             fmaxf(bf2f((ushort)v10[j]), bf2f((ushort)v11[j])));
            a8[j] += g * mv;
          }
        } else {                              // bilinear up from 16x16
          float sh2 = h * 0.5f - 0.25f, sw2 = w * 0.5f - 0.25f;
          float fh0 = floorf(sh2), fw0 = floorf(sw2);
          int h0 = (int)fh0, w0 = (int)fw0;
          float fh = sh2 - fh0, fw = sw2 - fw0;
          int h0c = h0 < 0 ? 0 : h0, h1c = (h0 + 1 > 15) ? 15 : h0 + 1;
          int w0c = w0 < 0 ? 0 : w0, w1c = (w0 + 1 > 15) ? 15 : w0 + 1;
          bf16x8 v00 = *(const bf16x8*)&cin[(size_t)(h0c * 16 + w0c) * 128 + q * 8];
          bf16x8 v01 = *(const bf16x8*)&cin[(size_t)(h0c * 16 + w1c) * 128 + q * 8];
          bf16x8 v10 = *(const bf16x8*)&cin[(size_t)(h1c * 16 + w0c) * 128 + q * 8];
          bf16x8 v11 = *(const bf16x8*)&cin[(size_t)(h1c * 16 + w1c) * 128 + q * 8];
          #pragma unroll
          for (int j = 0; j < 8; ++j) {
            float vv = (1.0f - fh) * ((1.0f - fw) * bf2f((ushort)v00[j]) + fw * bf2f((ushort)v01[j])) +
                       fh * ((1.0f - fw) * bf2f((ushort)v10[j]) + fw * bf2f((ushort)v11[j]));
            a8[j] += g * vv;
          }
        }
      }
      #pragma unroll
      for (int j = 0; j < 8; ++j) sh.sO[pxl * 129 + q * 8 + j] = a8[j];
    }
    __syncthreads();
    float* ob = out + (size_t)b * 131072;
    #pragma unroll 4
    for (int i = 0; i < 16; ++i) {
      int u = i * 256 + tid;
      int c = u >> 5, pxl = u & 31;
      ob[(size_t)c * 1024 + chunk * 32 + pxl] = sh.sO[pxl * 129 + c];
    }
  }
}

// ---------------------------------------------------------------------------
extern "C" void kernel_launch(void* const* d_in, const int* in_sizes, int n_in,
                              void* d_out, int out_size, void* d_ws, size_t ws_size,
                              hipStream_t stream) {
  const float* x   = (const float*)d_in[0];
  const float* tf  = (const float*)d_in[1];
  const float* Wx  = (const float*)d_in[2];
  const float* Wt  = (const float*)d_in[3];
  const float* cw1 = (const float*)d_in[4];
  const float* cb1 = (const float*)d_in[5];
  const float* cw2 = (const float*)d_in[6];
  const float* cb2 = (const float*)d_in[7];
  float* out = (float*)d_out;

  float*  wsf  = (float*)d_ws;
  ushort* wt2  = (ushort*)(wsf + 1024);
  ushort* buf0 = wt2 + 8 * (size_t)WT_ELEMS;
  ushort* buf1 = buf0 + 8 * (size_t)SLOT_ELEMS;

  void* args[13] = {
    (void*)&x, (void*)&tf, (void*)&Wx, (void*)&Wt,
    (void*)&cw1, (void*)&cb1, (void*)&cw2, (void*)&cb2,
    (void*)&out, (void*)&wsf, (void*)&wt2, (void*)&buf0, (void*)&buf1
  };
  hipLaunchCooperativeKernel((const void*)mega_kernel, dim3(512), dim3(256),
                             args, 0, stream);
}

// Round 5
// 162.045 us; speedup vs baseline: 2.1172x; 2.1172x over previous
//
#include <hip/hip_runtime.h>
#include <math.h>

// ---------------------------------------------------------------------------
// MMoE feed-forward, round 4: 5 kernels, work-list balanced MFMA conv.
//   K1 front : xp + wtrans(ALL 16 experts) + prep(ALL 12 variants)
//   K2 gate  : gate + mi_loss + conv work-list planner
//   K3 conv1 : worklist-driven implicit-GEMM (bias + fast GELU)
//   K4 conv2 : worklist-driven implicit-GEMM (bias)
//   K5 combine: post-transform * gate -> NCHW f32
//
// ws layout (elements):
//   wsf (f32) [0..4095]: wsi[0..7]=slot expert, wsi[8..15]=slot batch,
//                        wsf[16..23]=gate, wsf[64..575]=xp,
//                        wsi[600]=N work items, wsi[640..1151]=worklist
//   wt2 (bf16) 16*294912  all-expert weights, MFMA-frag order:
//              [e][which][k=tap*4+icc][oc16blk(0..7)][lane(0..63)][j(0..7)]
//   pbuf (bf16) 4*5376*128  prepped inputs [b][tp0:1024px|tp1:4096px|tp2:256px]
//   buf1 (bf16) 8*524288   conv1 out (per slot NHWC)
//   buf0 (bf16) 8*524288   conv2 out (per slot NHWC)
// ---------------------------------------------------------------------------

typedef __attribute__((ext_vector_type(8))) short bf16x8;
typedef __attribute__((ext_vector_type(4))) float f32x4;

#define SLOT_ELEMS 524288
#define WT_E       294912            // per expert (both convs)

__device__ inline ushort f2bf(float f) {
  unsigned u = __float_as_uint(f);
  return (ushort)((u + 0x7FFFu + ((u >> 16) & 1u)) >> 16);
}
__device__ inline float bf2f(ushort h) {
  return __uint_as_float(((unsigned)h) << 16);
}
__device__ inline float gelu_fast(float v) {      // tanh-form GELU, err<~4e-4
  float v2 = v * v;
  float z2 = v * fmaf(0.0713548162726f, v2, 1.59576912161f);
  float ex = __expf(-z2);
  return __fdividef(v, 1.0f + ex);
}

// ---------------- K1: xp + wtrans_all + prep_all ----------------------------
__global__ __launch_bounds__(256) void front_kernel(const float* __restrict__ x,
                                                    const float* __restrict__ cw1,
                                                    const float* __restrict__ cw2,
                                                    float* __restrict__ wsf,
                                                    ushort* __restrict__ wt2,
                                                    ushort* __restrict__ pbuf) {
  int bid = blockIdx.x, tid = threadIdx.x;
  __shared__ float red[4];
  __shared__ ushort sT[128 * 65];

  // ---- A: xp — (b,c) = bid ----
  {
    const float4* p = (const float4*)(x + (size_t)bid * 1024);
    float4 v = p[tid];
    float s = v.x + v.y + v.z + v.w;
    #pragma unroll
    for (int off = 32; off > 0; off >>= 1) s += __shfl_down(s, off);
    if ((tid & 63) == 0) red[tid >> 6] = s;
    __syncthreads();
    if (tid == 0)
      wsf[64 + bid] = (red[0] + red[1] + red[2] + red[3]) * (1.0f / 1024.0f);
  }

  // ---- B: wtrans for ALL 16 experts; block slice = 9216 elems ----
  {
    int base = bid * 9216;
    #pragma unroll 4
    for (int it = 0; it < 36; ++it) {
      int idx = base + it * 256 + tid;          // < 4718592
      int e = idx / WT_E;
      int r = idx - e * WT_E;
      int which = r / 147456; r -= which * 147456;
      int pos = r & 511;
      int chunk = r >> 9;
      int blk = chunk & 7;
      int t2 = chunk >> 3;
      int icc = t2 & 3, tap = t2 >> 2;
      int lane8 = pos >> 3, j = pos & 7;
      int oc = blk * 16 + (lane8 & 15);
      int ic = icc * 32 + (lane8 >> 4) * 8 + j;
      const float* src = which ? cw2 : cw1;
      wt2[idx] = f2bf(src[(((size_t)e * 128 + oc) * 128 + ic) * 9 + tap]);
    }
  }

  // ---- C: prep ALL 12 variants; 336 chunks of 64 px ----
  if (bid < 336) {
    int b = bid / 84, r = bid - (bid / 84) * 84;
    int tp, chunk, S, pp;
    if (r < 16)      { tp = 0; chunk = r;      S = 32; pp = 0; }
    else if (r < 80) { tp = 1; chunk = r - 16; S = 64; pp = 1024; }
    else             { tp = 2; chunk = r - 80; S = 16; pp = 5120; }
    const float* xb = x + (size_t)b * 131072;
    int pxl0 = tid & 63, c0 = tid >> 6;
    __syncthreads();
    #pragma unroll 4
    for (int i = 0; i < 32; ++i) {
      int c = i * 4 + c0;
      int px = chunk * 64 + pxl0;
      float v;
      if (tp == 0) {
        v = xb[c * 1024 + px];
      } else if (tp == 1) {
        int h = px >> 6, w = px & 63;
        v = xb[c * 1024 + (h >> 1) * 32 + (w >> 1)];
      } else {
        int h = px >> 4, w = px & 15;
        const float* p = xb + c * 1024 + (h << 1) * 32 + (w << 1);
        v = fmaxf(fmaxf(p[0], p[1]), fmaxf(p[32], p[33]));
      }
      sT[c * 65 + pxl0] = f2bf(v);
    }
    __syncthreads();
    ushort* ob = pbuf + ((size_t)b * 5376 + pp) * 128;
    #pragma unroll
    for (int i = 0; i < 4; ++i) {
      int u = i * 256 + tid;
      int pxl = u >> 4, q = u & 15;
      bf16x8 pk;
      #pragma unroll
      for (int j = 0; j < 8; ++j) pk[j] = (short)sT[(q * 8 + j) * 65 + pxl];
      *(bf16x8*)&ob[(size_t)(chunk * 64 + pxl) * 128 + q * 8] = pk;
    }
  }
}

// ---------------- K2: gate + mi_loss + planner ------------------------------
__global__ __launch_bounds__(256) void gate_kernel(const float* __restrict__ tf,
                                                   const float* __restrict__ Wx,
                                                   const float* __restrict__ Wt,
                                                   float* __restrict__ wsf,
                                                   float* __restrict__ out) {
  __shared__ float part[4][64];
  __shared__ float slog[64];
  __shared__ float sprob[64];
  __shared__ float ssum[4];
  int tid = threadIdx.x;
  int p = tid >> 6, be = tid & 63;
  int b = be >> 4, e = be & 15;
  const float* xp = wsf + 64;

  float acc = 0.0f;
  for (int c = p * 32; c < p * 32 + 32; ++c) acc += xp[b * 128 + c] * Wx[c * 16 + e];
  for (int d = p * 128; d < p * 128 + 128; ++d) acc += tf[b * 512 + d] * Wt[d * 16 + e];
  part[p][be] = acc;
  __syncthreads();

  if (tid < 64) slog[be] = part[0][be] + part[1][be] + part[2][be] + part[3][be];
  __syncthreads();
  if (tid < 64) {
    float m = slog[b * 16];
    for (int j = 1; j < 16; ++j) m = fmaxf(m, slog[b * 16 + j]);
    sprob[be] = expf(slog[be] - m);
  }
  __syncthreads();
  if (tid < 4) {                            // tid = b
    float s = 0.0f;
    for (int j = 0; j < 16; ++j) s += sprob[tid * 16 + j];
    ssum[tid] = s;
    int i1 = 0; float v1 = -1.0f;
    for (int j = 0; j < 16; ++j) {
      float v = sprob[tid * 16 + j];
      if (v > v1) { v1 = v; i1 = j; }
    }
    int i2 = -1; float v2 = -1.0f;
    for (int j = 0; j < 16; ++j) {
      if (j == i1) continue;
      float v = sprob[tid * 16 + j];
      if (v > v2) { v2 = v; i2 = j; }
    }
    float inv = 1.0f / (v1 + v2);           // softmax denom cancels
    int* wsi = (int*)wsf;
    wsi[2 * tid]     = i1;  wsi[2 * tid + 1]     = i2;
    wsi[8 + 2 * tid] = tid; wsi[8 + 2 * tid + 1] = tid;
    wsf[16 + 2 * tid]     = v1 * inv;
    wsf[16 + 2 * tid + 1] = v2 * inv;
  }
  __syncthreads();
  if (tid == 0) {
    float kl = 0.0f;
    for (int j = 0; j < 16; ++j) {
      float pe = 0.25f * (sprob[j] / ssum[0] + sprob[16 + j] / ssum[1] +
                          sprob[32 + j] / ssum[2] + sprob[48 + j] / ssum[3]);
      kl += pe * logf(pe / (pe + 1e-7f) + 1e-7f);
    }
    out[524288] = -0.01f * kl;              // mi_loss
  } else if (tid == 64) {
    // planner: compact work list, tile-major interleave across slots
    int* wsi = (int*)wsf;
    int n = 0;
    for (int t = 0; t < 64; ++t) {
      for (int s = 0; s < 8; ++s) {
        int ee = wsi[s];
        int tp = ee % 3;
        int ntile = (tp == 0) ? 16 : ((tp == 1) ? 64 : 4);
        if (t < ntile) {
          int bb = wsi[8 + s];
          wsi[640 + n] = s | (t << 4) | (ee << 12) | (tp << 16) | (bb << 20);
          ++n;
        }
      }
    }
    wsi[600] = n;
  }
}

// ---------------- K3/K4: conv3x3 via MFMA implicit GEMM ---------------------
// worklist-driven; block = 128 oc x 64 px (8x8); 4 waves x (32 oc x 64 px)
__global__ __launch_bounds__(256, 2) void conv_mfma(const float* __restrict__ wsf,
                                                    const ushort* __restrict__ pbuf,
                                                    ushort* __restrict__ buf1,
                                                    ushort* __restrict__ buf0,
                                                    const ushort* __restrict__ wt2,
                                                    int which,
                                                    const float* __restrict__ ball,
                                                    int gelu) {
  const int* wsi = (const int*)wsf;
  int bid = blockIdx.x;
  if (bid >= wsi[600]) return;
  int ent = wsi[640 + bid];
  int slot = ent & 7;
  int tile = (ent >> 4) & 63;
  int e    = (ent >> 12) & 15;
  int tp   = (ent >> 16) & 3;
  int b    = (ent >> 20) & 3;
  int S = (tp == 0) ? 32 : ((tp == 1) ? 64 : 16);
  int tpr = S >> 3;
  int tr = (tile / tpr) << 3;
  int tc = (tile % tpr) << 3;

  const ushort* in = which
      ? (buf1 + (size_t)slot * SLOT_ELEMS)
      : (pbuf + ((size_t)b * 5376 + (tp == 0 ? 0 : (tp == 1 ? 1024 : 5120))) * 128);
  ushort* outp = (which ? buf0 : buf1) + (size_t)slot * SLOT_ELEMS;

  __shared__ ushort sIn[100 * 136];       // [halo px][128 ch + 8 pad]
  int tid = threadIdx.x;

  for (int u = tid; u < 1600; u += 256) {
    int p = u >> 4, q = u & 15;
    int hr = p / 10, wc = p - hr * 10;
    int gh = tr + hr - 1, gw = tc + wc - 1;
    bf16x8 v = {0, 0, 0, 0, 0, 0, 0, 0};
    if (gh >= 0 && gh < S && gw >= 0 && gw < S)
      v = *(const bf16x8*)&in[(size_t)(gh * S + gw) * 128 + q * 8];
    *(bf16x8*)&sIn[p * 136 + q * 8] = v;
  }

  int wid = tid >> 6, lane = tid & 63;
  int ln = lane & 15, lg = lane >> 4;
  int ocw = wid << 5;
  const float* bias = ball + e * 128;

  // bias folded into acc init: row oc = m*16 + lg*4 + j
  f32x4 acc[2][4];
  #pragma unroll
  for (int m = 0; m < 2; ++m) {
    #pragma unroll
    for (int j = 0; j < 4; ++j) {
      float bv = bias[ocw + m * 16 + lg * 4 + j];
      #pragma unroll
      for (int n = 0; n < 4; ++n) acc[m][n][j] = bv;
    }
  }

  int pxb[4];
  #pragma unroll
  for (int n = 0; n < 4; ++n) {
    int px = n * 16 + ln;
    pxb[n] = (px >> 3) * 10 + (px & 7);
  }

  const ushort* wbase = wt2 + ((size_t)e * 2 + which) * 147456
                        + (size_t)(wid * 2) * 512 + lane * 8;

  bf16x8 abuf[3][2];
  #pragma unroll
  for (int i = 0; i < 2; ++i) {
    abuf[i][0] = *(const bf16x8*)&wbase[(size_t)i * 4096];
    abuf[i][1] = *(const bf16x8*)&wbase[(size_t)i * 4096 + 512];
  }

  __syncthreads();

  #pragma unroll 6
  for (int kk = 0; kk < 36; ++kk) {          // k = tap*4 + icc
    if (kk + 2 < 36) {
      abuf[(kk + 2) % 3][0] = *(const bf16x8*)&wbase[(size_t)(kk + 2) * 4096];
      abuf[(kk + 2) % 3][1] = *(const bf16x8*)&wbase[(size_t)(kk + 2) * 4096 + 512];
    }
    int tap = kk >> 2, icc = kk & 3;
    int off = (tap / 3) * 10 + (tap % 3);
    bf16x8 bfr[4];
    #pragma unroll
    for (int n = 0; n < 4; ++n)
      bfr[n] = *(bf16x8*)&sIn[(pxb[n] + off) * 136 + icc * 32 + lg * 8];
    #pragma unroll
    for (int m = 0; m < 2; ++m)
      #pragma unroll
      for (int n = 0; n < 4; ++n)
        acc[m][n] = __builtin_amdgcn_mfma_f32_16x16x32_bf16(abuf[kk % 3][m], bfr[n],
                                                            acc[m][n], 0, 0, 0);
  }

  #pragma unroll
  for (int m = 0; m < 2; ++m) {
    int oc0 = ocw + m * 16 + lg * 4;
    #pragma unroll
    for (int n = 0; n < 4; ++n) {
      int px = n * 16 + ln;
      int gh = tr + (px >> 3), gw = tc + (px & 7);
      float v0 = acc[m][n][0];
      float v1 = acc[m][n][1];
      float v2 = acc[m][n][2];
      float v3 = acc[m][n][3];
      if (gelu) {
        v0 = gelu_fast(v0); v1 = gelu_fast(v1);
        v2 = gelu_fast(v2); v3 = gelu_fast(v3);
      }
      unsigned pk0 = (unsigned)f2bf(v0) | ((unsigned)f2bf(v1) << 16);
      unsigned pk1 = (unsigned)f2bf(v2) | ((unsigned)f2bf(v3) << 16);
      uint2 st; st.x = pk0; st.y = pk1;
      *(uint2*)&outp[(size_t)(gh * S + gw) * 128 + oc0] = st;
    }
  }
}

// ---------------- K5: combine — post * gate, NHWC bf16 -> NCHW f32 ----------
__global__ __launch_bounds__(256) void combine_kernel(const float* __restrict__ wsf,
                                                      const ushort* __restrict__ bufc,
                                                      float* __restrict__ out) {
  const int* wsi = (const int*)wsf;
  int chunk = blockIdx.x, b = blockIdx.y;   // 32 chunks x 32 px
  __shared__ float sO[32 * 129];
  int tid = threadIdx.x;

  #pragma unroll
  for (int i = 0; i < 2; ++i) {
    int u = i * 256 + tid;
    int pxl = u >> 4, q = u & 15;
    int px = chunk * 32 + pxl;
    int h = px >> 5, w = px & 31;
    float a8[8];
    #pragma unroll
    for (int j = 0; j < 8; ++j) a8[j] = 0.0f;

    for (int s = 0; s < 2; ++s) {
      int slot = 2 * b + s;
      int e = wsi[slot];
      float g = wsf[16 + slot];
      int tp = e % 3;
      const ushort* cin = bufc + (size_t)slot * SLOT_ELEMS;
      if (tp == 0) {
        bf16x8 v = *(const bf16x8*)&cin[(size_t)(h * 32 + w) * 128 + q * 8];
        #pragma unroll
        for (int j = 0; j < 8; ++j) a8[j] += g * bf2f((ushort)v[j]);
      } else if (tp == 1) {                 // maxpool from 64x64
        bf16x8 v00 = *(const bf16x8*)&cin[(size_t)((2*h) * 64 + 2*w) * 128 + q * 8];
        bf16x8 v01 = *(const bf16x8*)&cin[(size_t)((2*h) * 64 + 2*w + 1) * 128 + q * 8];
        bf16x8 v10 = *(const bf16x8*)&cin[(size_t)((2*h+1) * 64 + 2*w) * 128 + q * 8];
        bf16x8 v11 = *(const bf16x8*)&cin[(size_t)((2*h+1) * 64 + 2*w + 1) * 128 + q * 8];
        #pragma unroll
        for (int j = 0; j < 8; ++j) {
          float mv = fmaxf(fmaxf(bf2f((ushort)v00[j]), bf2f((ushort)v01[j])),
                           fmaxf(bf2f((ushort)v10[j]), bf2f((ushort)v11[j])));
          a8[j] += g * mv;
        }
      } else {                              // bilinear up from 16x16
        float sh2 = h * 0.5f - 0.25f, sw2 = w * 0.5f - 0.25f;
        float fh0 = floorf(sh2), fw0 = floorf(sw2);
        int h0 = (int)fh0, w0 = (int)fw0;
        float fh = sh2 - fh0, fw = sw2 - fw0;
        int h0c = h0 < 0 ? 0 : h0, h1c = (h0 + 1 > 15) ? 15 : h0 + 1;
        int w0c = w0 < 0 ? 0 : w0, w1c = (w0 + 1 > 15) ? 15 : w0 + 1;
        bf16x8 v00 = *(const bf16x8*)&cin[(size_t)(h0c * 16 + w0c) * 128 + q * 8];
        bf16x8 v01 = *(const bf16x8*)&cin[(size_t)(h0c * 16 + w1c) * 128 + q * 8];
        bf16x8 v10 = *(const bf16x8*)&cin[(size_t)(h1c * 16 + w0c) * 128 + q * 8];
        bf16x8 v11 = *(const bf16x8*)&cin[(size_t)(h1c * 16 + w1c) * 128 + q * 8];
        #pragma unroll
        for (int j = 0; j < 8; ++j) {
          float vv = (1.0f - fh) * ((1.0f - fw) * bf2f((ushort)v00[j]) + fw * bf2f((ushort)v01[j])) +
                     fh * ((1.0f - fw) * bf2f((ushort)v10[j]) + fw * bf2f((ushort)v11[j]));
          a8[j] += g * vv;
        }
      }
    }
    #pragma unroll
    for (int j = 0; j < 8; ++j) sO[pxl * 129 + q * 8 + j] = a8[j];
  }
  __syncthreads();
  float* ob = out + (size_t)b * 131072;
  #pragma unroll 4
  for (int i = 0; i < 16; ++i) {
    int u = i * 256 + tid;
    int c = u >> 5, pxl = u & 31;
    ob[(size_t)c * 1024 + chunk * 32 + pxl] = sO[pxl * 129 + c];
  }
}

// ---------------------------------------------------------------------------
extern "C" void kernel_launch(void* const* d_in, const int* in_sizes, int n_in,
                              void* d_out, int out_size, void* d_ws, size_t ws_size,
                              hipStream_t stream) {
  const float* x   = (const float*)d_in[0];
  const float* tf  = (const float*)d_in[1];
  const float* Wx  = (const float*)d_in[2];
  const float* Wt  = (const float*)d_in[3];
  const float* cw1 = (const float*)d_in[4];
  const float* cb1 = (const float*)d_in[5];
  const float* cw2 = (const float*)d_in[6];
  const float* cb2 = (const float*)d_in[7];
  float* out = (float*)d_out;

  float*  wsf  = (float*)d_ws;                    // 4096 f32
  ushort* wt2  = (ushort*)(wsf + 4096);           // 16*294912
  ushort* pbuf = wt2 + 16 * (size_t)WT_E;         // 4*5376*128
  ushort* buf1 = pbuf + 4 * 5376 * 128;           // 8*524288
  ushort* buf0 = buf1 + 8 * (size_t)SLOT_ELEMS;   // 8*524288

  hipLaunchKernelGGL(front_kernel,   dim3(512),    dim3(256), 0, stream, x, cw1, cw2, wsf, wt2, pbuf);
  hipLaunchKernelGGL(gate_kernel,    dim3(1),      dim3(256), 0, stream, tf, Wx, Wt, wsf, out);
  hipLaunchKernelGGL(conv_mfma,      dim3(512),    dim3(256), 0, stream, wsf, pbuf, buf1, buf0, wt2, 0, cb1, 1);
  hipLaunchKernelGGL(conv_mfma,      dim3(512),    dim3(256), 0, stream, wsf, pbuf, buf1, buf0, wt2, 1, cb2, 0);
  hipLaunchKernelGGL(combine_kernel, dim3(32, 4),  dim3(256), 0, stream, wsf, buf0, out);
}

// Round 6
// 93.461 us; speedup vs baseline: 3.6708x; 1.7338x over previous
//
#include <hip/hip_runtime.h>
#include <math.h>

// ---------------------------------------------------------------------------
// MMoE feed-forward, round 5: fix latency-bound gate planner (LDS + parallel
// emit); rest = round-4 worklist-balanced MFMA conv structure.
//   K1 front : xp + wtrans(ALL 16 experts) + prep(ALL 12 variants)
//   K2 gate  : gate + mi_loss + conv work-list planner (parallel)
//   K3 conv1 : worklist-driven implicit-GEMM (bias + fast GELU)
//   K4 conv2 : worklist-driven implicit-GEMM (bias)
//   K5 combine: post-transform * gate -> NCHW f32
//
// ws layout (elements):
//   wsf (f32) [0..4095]: wsi[0..7]=slot expert, wsi[8..15]=slot batch,
//                        wsf[16..23]=gate, wsf[64..575]=xp,
//                        wsi[600]=N work items, wsi[640..1151]=worklist
//   wt2 (bf16) 16*294912  all-expert weights, MFMA-frag order:
//              [e][which][k=tap*4+icc][oc16blk(0..7)][lane(0..63)][j(0..7)]
//   pbuf (bf16) 4*5376*128  prepped inputs [b][tp0:1024px|tp1:4096px|tp2:256px]
//   buf1 (bf16) 8*524288   conv1 out (per slot NHWC)
//   buf0 (bf16) 8*524288   conv2 out (per slot NHWC)
// ---------------------------------------------------------------------------

typedef __attribute__((ext_vector_type(8))) short bf16x8;
typedef __attribute__((ext_vector_type(4))) float f32x4;

#define SLOT_ELEMS 524288
#define WT_E       294912            // per expert (both convs)

__device__ inline ushort f2bf(float f) {
  unsigned u = __float_as_uint(f);
  return (ushort)((u + 0x7FFFu + ((u >> 16) & 1u)) >> 16);
}
__device__ inline float bf2f(ushort h) {
  return __uint_as_float(((unsigned)h) << 16);
}
__device__ inline float gelu_fast(float v) {      // tanh-form GELU, err<~4e-4
  float v2 = v * v;
  float z2 = v * fmaf(0.0713548162726f, v2, 1.59576912161f);
  float ex = __expf(-z2);
  return __fdividef(v, 1.0f + ex);
}

// ---------------- K1: xp + wtrans_all + prep_all ----------------------------
__global__ __launch_bounds__(256) void front_kernel(const float* __restrict__ x,
                                                    const float* __restrict__ cw1,
                                                    const float* __restrict__ cw2,
                                                    float* __restrict__ wsf,
                                                    ushort* __restrict__ wt2,
                                                    ushort* __restrict__ pbuf) {
  int bid = blockIdx.x, tid = threadIdx.x;
  __shared__ float red[4];
  __shared__ ushort sT[128 * 65];

  // ---- A: xp — (b,c) = bid ----
  {
    const float4* p = (const float4*)(x + (size_t)bid * 1024);
    float4 v = p[tid];
    float s = v.x + v.y + v.z + v.w;
    #pragma unroll
    for (int off = 32; off > 0; off >>= 1) s += __shfl_down(s, off);
    if ((tid & 63) == 0) red[tid >> 6] = s;
    __syncthreads();
    if (tid == 0)
      wsf[64 + bid] = (red[0] + red[1] + red[2] + red[3]) * (1.0f / 1024.0f);
  }

  // ---- B: wtrans for ALL 16 experts; block slice = 9216 elems ----
  {
    int base = bid * 9216;
    #pragma unroll 4
    for (int it = 0; it < 36; ++it) {
      int idx = base + it * 256 + tid;          // < 4718592
      int e = idx / WT_E;
      int r = idx - e * WT_E;
      int which = r / 147456; r -= which * 147456;
      int pos = r & 511;
      int chunk = r >> 9;
      int blk = chunk & 7;
      int t2 = chunk >> 3;
      int icc = t2 & 3, tap = t2 >> 2;
      int lane8 = pos >> 3, j = pos & 7;
      int oc = blk * 16 + (lane8 & 15);
      int ic = icc * 32 + (lane8 >> 4) * 8 + j;
      const float* src = which ? cw2 : cw1;
      wt2[idx] = f2bf(src[(((size_t)e * 128 + oc) * 128 + ic) * 9 + tap]);
    }
  }

  // ---- C: prep ALL 12 variants; 336 chunks of 64 px ----
  if (bid < 336) {
    int b = bid / 84, r = bid - (bid / 84) * 84;
    int tp, chunk, S, pp;
    if (r < 16)      { tp = 0; chunk = r;      S = 32; pp = 0; }
    else if (r < 80) { tp = 1; chunk = r - 16; S = 64; pp = 1024; }
    else             { tp = 2; chunk = r - 80; S = 16; pp = 5120; }
    const float* xb = x + (size_t)b * 131072;
    int pxl0 = tid & 63, c0 = tid >> 6;
    __syncthreads();
    #pragma unroll 4
    for (int i = 0; i < 32; ++i) {
      int c = i * 4 + c0;
      int px = chunk * 64 + pxl0;
      float v;
      if (tp == 0) {
        v = xb[c * 1024 + px];
      } else if (tp == 1) {
        int h = px >> 6, w = px & 63;
        v = xb[c * 1024 + (h >> 1) * 32 + (w >> 1)];
      } else {
        int h = px >> 4, w = px & 15;
        const float* p = xb + c * 1024 + (h << 1) * 32 + (w << 1);
        v = fmaxf(fmaxf(p[0], p[1]), fmaxf(p[32], p[33]));
      }
      sT[c * 65 + pxl0] = f2bf(v);
    }
    __syncthreads();
    ushort* ob = pbuf + ((size_t)b * 5376 + pp) * 128;
    #pragma unroll
    for (int i = 0; i < 4; ++i) {
      int u = i * 256 + tid;
      int pxl = u >> 4, q = u & 15;
      bf16x8 pk;
      #pragma unroll
      for (int j = 0; j < 8; ++j) pk[j] = (short)sT[(q * 8 + j) * 65 + pxl];
      *(bf16x8*)&ob[(size_t)(chunk * 64 + pxl) * 128 + q * 8] = pk;
    }
  }
}

// ---------------- K2: gate + mi_loss + planner (parallel) -------------------
__global__ __launch_bounds__(256) void gate_kernel(const float* __restrict__ tf,
                                                   const float* __restrict__ Wx,
                                                   const float* __restrict__ Wt,
                                                   float* __restrict__ wsf,
                                                   float* __restrict__ out) {
  __shared__ float part[4][64];
  __shared__ float slog[64];
  __shared__ float sprob[64];
  __shared__ float ssum[4];
  __shared__ int   se[16];          // slot -> expert (post top-2)
  __shared__ int   snt[8];          // slot -> tile count
  int tid = threadIdx.x;
  int p = tid >> 6, be = tid & 63;
  int b = be >> 4, e = be & 15;
  const float* xp = wsf + 64;

  float acc = 0.0f;
  #pragma unroll 8
  for (int c = p * 32; c < p * 32 + 32; ++c)
    acc += xp[b * 128 + c] * Wx[c * 16 + e];
  {
    const float4* tf4 = (const float4*)(tf + b * 512 + p * 128);
    #pragma unroll 8
    for (int d4 = 0; d4 < 32; ++d4) {
      float4 t4 = tf4[d4];
      int d = p * 128 + d4 * 4;
      acc += t4.x * Wt[(d + 0) * 16 + e];
      acc += t4.y * Wt[(d + 1) * 16 + e];
      acc += t4.z * Wt[(d + 2) * 16 + e];
      acc += t4.w * Wt[(d + 3) * 16 + e];
    }
  }
  part[p][be] = acc;
  __syncthreads();

  if (tid < 64) slog[be] = part[0][be] + part[1][be] + part[2][be] + part[3][be];
  __syncthreads();
  if (tid < 64) {
    float m = slog[b * 16];
    for (int j = 1; j < 16; ++j) m = fmaxf(m, slog[b * 16 + j]);
    sprob[be] = expf(slog[be] - m);
  }
  __syncthreads();
  if (tid < 4) {                            // tid = b
    float s = 0.0f;
    for (int j = 0; j < 16; ++j) s += sprob[tid * 16 + j];
    ssum[tid] = s;
    int i1 = 0; float v1 = -1.0f;
    for (int j = 0; j < 16; ++j) {
      float v = sprob[tid * 16 + j];
      if (v > v1) { v1 = v; i1 = j; }
    }
    int i2 = -1; float v2 = -1.0f;
    for (int j = 0; j < 16; ++j) {
      if (j == i1) continue;
      float v = sprob[tid * 16 + j];
      if (v > v2) { v2 = v; i2 = j; }
    }
    float inv = 1.0f / (v1 + v2);           // softmax denom cancels
    int* wsi = (int*)wsf;
    wsi[2 * tid]     = i1;  wsi[2 * tid + 1]     = i2;
    wsi[8 + 2 * tid] = tid; wsi[8 + 2 * tid + 1] = tid;
    wsf[16 + 2 * tid]     = v1 * inv;
    wsf[16 + 2 * tid + 1] = v2 * inv;
    se[2 * tid] = i1; se[2 * tid + 1] = i2;
  }
  __syncthreads();
  if (tid < 8) {
    int ee = se[tid];
    int tp = ee % 3;
    snt[tid] = (tp == 0) ? 16 : ((tp == 1) ? 64 : 4);
  }
  __syncthreads();
  if (tid < 8) {                            // parallel planner: stores only
    int pre = 0;
    #pragma unroll
    for (int s = 0; s < 8; ++s) pre += (s < tid) ? snt[s] : 0;
    int ee = se[tid];
    int tp = ee % 3;
    int nt = snt[tid];
    int bb = tid >> 1;
    int ent_base = tid | (ee << 12) | (tp << 16) | (bb << 20);
    int* wl = (int*)wsf + 640;
    for (int t = 0; t < nt; ++t) wl[pre + t] = ent_base | (t << 4);
    if (tid == 7) ((int*)wsf)[600] = pre + nt;
  } else if (tid == 8) {
    // nothing
  }
  if (tid == 32) {
    float kl = 0.0f;
    for (int j = 0; j < 16; ++j) {
      float pe = 0.25f * (sprob[j] / ssum[0] + sprob[16 + j] / ssum[1] +
                          sprob[32 + j] / ssum[2] + sprob[48 + j] / ssum[3]);
      kl += pe * logf(pe / (pe + 1e-7f) + 1e-7f);
    }
    out[524288] = -0.01f * kl;              // mi_loss
  }
}

// ---------------- K3/K4: conv3x3 via MFMA implicit GEMM ---------------------
// worklist-driven; block = 128 oc x 64 px (8x8); 4 waves x (32 oc x 64 px)
__global__ __launch_bounds__(256, 2) void conv_mfma(const float* __restrict__ wsf,
                                                    const ushort* __restrict__ pbuf,
                                                    ushort* __restrict__ buf1,
                                                    ushort* __restrict__ buf0,
                                                    const ushort* __restrict__ wt2,
                                                    int which,
                                                    const float* __restrict__ ball,
                                                    int gelu) {
  const int* wsi = (const int*)wsf;
  int bid = blockIdx.x;
  if (bid >= wsi[600]) return;
  int ent = wsi[640 + bid];
  int slot = ent & 7;
  int tile = (ent >> 4) & 63;
  int e    = (ent >> 12) & 15;
  int tp   = (ent >> 16) & 3;
  int b    = (ent >> 20) & 3;
  int S = (tp == 0) ? 32 : ((tp == 1) ? 64 : 16);
  int tpr = S >> 3;
  int tr = (tile / tpr) << 3;
  int tc = (tile % tpr) << 3;

  const ushort* in = which
      ? (buf1 + (size_t)slot * SLOT_ELEMS)
      : (pbuf + ((size_t)b * 5376 + (tp == 0 ? 0 : (tp == 1 ? 1024 : 5120))) * 128);
  ushort* outp = (which ? buf0 : buf1) + (size_t)slot * SLOT_ELEMS;

  __shared__ ushort sIn[100 * 136];       // [halo px][128 ch + 8 pad]
  int tid = threadIdx.x;

  for (int u = tid; u < 1600; u += 256) {
    int p = u >> 4, q = u & 15;
    int hr = p / 10, wc = p - hr * 10;
    int gh = tr + hr - 1, gw = tc + wc - 1;
    bf16x8 v = {0, 0, 0, 0, 0, 0, 0, 0};
    if (gh >= 0 && gh < S && gw >= 0 && gw < S)
      v = *(const bf16x8*)&in[(size_t)(gh * S + gw) * 128 + q * 8];
    *(bf16x8*)&sIn[p * 136 + q * 8] = v;
  }

  int wid = tid >> 6, lane = tid & 63;
  int ln = lane & 15, lg = lane >> 4;
  int ocw = wid << 5;
  const float* bias = ball + e * 128;

  // bias folded into acc init: row oc = m*16 + lg*4 + j
  f32x4 acc[2][4];
  #pragma unroll
  for (int m = 0; m < 2; ++m) {
    #pragma unroll
    for (int j = 0; j < 4; ++j) {
      float bv = bias[ocw + m * 16 + lg * 4 + j];
      #pragma unroll
      for (int n = 0; n < 4; ++n) acc[m][n][j] = bv;
    }
  }

  int pxb[4];
  #pragma unroll
  for (int n = 0; n < 4; ++n) {
    int px = n * 16 + ln;
    pxb[n] = (px >> 3) * 10 + (px & 7);
  }

  const ushort* wbase = wt2 + ((size_t)e * 2 + which) * 147456
                        + (size_t)(wid * 2) * 512 + lane * 8;

  bf16x8 abuf[3][2];
  #pragma unroll
  for (int i = 0; i < 2; ++i) {
    abuf[i][0] = *(const bf16x8*)&wbase[(size_t)i * 4096];
    abuf[i][1] = *(const bf16x8*)&wbase[(size_t)i * 4096 + 512];
  }

  __syncthreads();

  #pragma unroll 6
  for (int kk = 0; kk < 36; ++kk) {          // k = tap*4 + icc
    if (kk + 2 < 36) {
      abuf[(kk + 2) % 3][0] = *(const bf16x8*)&wbase[(size_t)(kk + 2) * 4096];
      abuf[(kk + 2) % 3][1] = *(const bf16x8*)&wbase[(size_t)(kk + 2) * 4096 + 512];
    }
    int tap = kk >> 2, icc = kk & 3;
    int off = (tap / 3) * 10 + (tap % 3);
    bf16x8 bfr[4];
    #pragma unroll
    for (int n = 0; n < 4; ++n)
      bfr[n] = *(bf16x8*)&sIn[(pxb[n] + off) * 136 + icc * 32 + lg * 8];
    #pragma unroll
    for (int m = 0; m < 2; ++m)
      #pragma unroll
      for (int n = 0; n < 4; ++n)
        acc[m][n] = __builtin_amdgcn_mfma_f32_16x16x32_bf16(abuf[kk % 3][m], bfr[n],
                                                            acc[m][n], 0, 0, 0);
  }

  #pragma unroll
  for (int m = 0; m < 2; ++m) {
    int oc0 = ocw + m * 16 + lg * 4;
    #pragma unroll
    for (int n = 0; n < 4; ++n) {
      int px = n * 16 + ln;
      int gh = tr + (px >> 3), gw = tc + (px & 7);
      float v0 = acc[m][n][0];
      float v1 = acc[m][n][1];
      float v2 = acc[m][n][2];
      float v3 = acc[m][n][3];
      if (gelu) {
        v0 = gelu_fast(v0); v1 = gelu_fast(v1);
        v2 = gelu_fast(v2); v3 = gelu_fast(v3);
      }
      unsigned pk0 = (unsigned)f2bf(v0) | ((unsigned)f2bf(v1) << 16);
      unsigned pk1 = (unsigned)f2bf(v2) | ((unsigned)f2bf(v3) << 16);
      uint2 st; st.x = pk0; st.y = pk1;
      *(uint2*)&outp[(size_t)(gh * S + gw) * 128 + oc0] = st;
    }
  }
}

// ---------------- K5: combine — post * gate, NHWC bf16 -> NCHW f32 ----------
__global__ __launch_bounds__(256) void combine_kernel(const float* __restrict__ wsf,
                                                      const ushort* __restrict__ bufc,
                                                      float* __restrict__ out) {
  const int* wsi = (const int*)wsf;
  int chunk = blockIdx.x, b = blockIdx.y;   // 32 chunks x 32 px
  __shared__ float sO[32 * 129];
  int tid = threadIdx.x;

  #pragma unroll
  for (int i = 0; i < 2; ++i) {
    int u = i * 256 + tid;
    int pxl = u >> 4, q = u & 15;
    int px = chunk * 32 + pxl;
    int h = px >> 5, w = px & 31;
    float a8[8];
    #pragma unroll
    for (int j = 0; j < 8; ++j) a8[j] = 0.0f;

    for (int s = 0; s < 2; ++s) {
      int slot = 2 * b + s;
      int e = wsi[slot];
      float g = wsf[16 + slot];
      int tp = e % 3;
      const ushort* cin = bufc + (size_t)slot * SLOT_ELEMS;
      if (tp == 0) {
        bf16x8 v = *(const bf16x8*)&cin[(size_t)(h * 32 + w) * 128 + q * 8];
        #pragma unroll
        for (int j = 0; j < 8; ++j) a8[j] += g * bf2f((ushort)v[j]);
      } else if (tp == 1) {                 // maxpool from 64x64
        bf16x8 v00 = *(const bf16x8*)&cin[(size_t)((2*h) * 64 + 2*w) * 128 + q * 8];
        bf16x8 v01 = *(const bf16x8*)&cin[(size_t)((2*h) * 64 + 2*w + 1) * 128 + q * 8];
        bf16x8 v10 = *(const bf16x8*)&cin[(size_t)((2*h+1) * 64 + 2*w) * 128 + q * 8];
        bf16x8 v11 = *(const bf16x8*)&cin[(size_t)((2*h+1) * 64 + 2*w + 1) * 128 + q * 8];
        #pragma unroll
        for (int j = 0; j < 8; ++j) {
          float mv = fmaxf(fmaxf(bf2f((ushort)v00[j]), bf2f((ushort)v01[j])),
                           fmaxf(bf2f((ushort)v10[j]), bf2f((ushort)v11[j])));
          a8[j] += g * mv;
        }
      } else {                              // bilinear up from 16x16
        float sh2 = h * 0.5f - 0.25f, sw2 = w * 0.5f - 0.25f;
        float fh0 = floorf(sh2), fw0 = floorf(sw2);
        int h0 = (int)fh0, w0 = (int)fw0;
        float fh = sh2 - fh0, fw = sw2 - fw0;
        int h0c = h0 < 0 ? 0 : h0, h1c = (h0 + 1 > 15) ? 15 : h0 + 1;
        int w0c = w0 < 0 ? 0 : w0, w1c = (w0 + 1 > 15) ? 15 : w0 + 1;
        bf16x8 v00 = *(const bf16x8*)&cin[(size_t)(h0c * 16 + w0c) * 128 + q * 8];
        bf16x8 v01 = *(const bf16x8*)&cin[(size_t)(h0c * 16 + w1c) * 128 + q * 8];
        bf16x8 v10 = *(const bf16x8*)&cin[(size_t)(h1c * 16 + w0c) * 128 + q * 8];
        bf16x8 v11 = *(const bf16x8*)&cin[(size_t)(h1c * 16 + w1c) * 128 + q * 8];
        #pragma unroll
        for (int j = 0; j < 8; ++j) {
          float vv = (1.0f - fh) * ((1.0f - fw) * bf2f((ushort)v00[j]) + fw * bf2f((ushort)v01[j])) +
                     fh * ((1.0f - fw) * bf2f((ushort)v10[j]) + fw * bf2f((ushort)v11[j]));
          a8[j] += g * vv;
        }
      }
    }
    #pragma unroll
    for (int j = 0; j < 8; ++j) sO[pxl * 129 + q * 8 + j] = a8[j];
  }
  __syncthreads();
  float* ob = out + (size_t)b * 131072;
  #pragma unroll 4
  for (int i = 0; i < 16; ++i) {
    int u = i * 256 + tid;
    int c = u >> 5, pxl = u & 31;
    ob[(size_t)c * 1024 + chunk * 32 + pxl] = sO[pxl * 129 + c];
  }
}

// ---------------------------------------------------------------------------
extern "C" void kernel_launch(void* const* d_in, const int* in_sizes, int n_in,
                              void* d_out, int out_size, void* d_ws, size_t ws_size,
                              hipStream_t stream) {
  const float* x   = (const float*)d_in[0];
  const float* tf  = (const float*)d_in[1];
  const float* Wx  = (const float*)d_in[2];
  const float* Wt  = (const float*)d_in[3];
  const float* cw1 = (const float*)d_in[4];
  const float* cb1 = (const float*)d_in[5];
  const float* cw2 = (const float*)d_in[6];
  const float* cb2 = (const float*)d_in[7];
  float* out = (float*)d_out;

  float*  wsf  = (float*)d_ws;                    // 4096 f32
  ushort* wt2  = (ushort*)(wsf + 4096);           // 16*294912
  ushort* pbuf = wt2 + 16 * (size_t)WT_E;         // 4*5376*128
  ushort* buf1 = pbuf + 4 * 5376 * 128;           // 8*524288
  ushort* buf0 = buf1 + 8 * (size_t)SLOT_ELEMS;   // 8*524288

  hipLaunchKernelGGL(front_kernel,   dim3(512),    dim3(256), 0, stream, x, cw1, cw2, wsf, wt2, pbuf);
  hipLaunchKernelGGL(gate_kernel,    dim3(1),      dim3(256), 0, stream, tf, Wx, Wt, wsf, out);
  hipLaunchKernelGGL(conv_mfma,      dim3(512),    dim3(256), 0, stream, wsf, pbuf, buf1, buf0, wt2, 0, cb1, 1);
  hipLaunchKernelGGL(conv_mfma,      dim3(512),    dim3(256), 0, stream, wsf, pbuf, buf1, buf0, wt2, 1, cb2, 0);
  hipLaunchKernelGGL(combine_kernel, dim3(32, 4),  dim3(256), 0, stream, wsf, buf0, out);
}

// Round 7
// 68.474 us; speedup vs baseline: 5.0103x; 1.3649x over previous
//
#include <hip/hip_runtime.h>
#include <math.h>

// ---------------------------------------------------------------------------
// MMoE feed-forward, round 6: coalesced LDS-transpose wtrans in front kernel
// (fixes 4x HBM read amplification), conv B-frag double-buffering.
//   K1 front : xp + wtrans(ALL 16 experts, LDS transpose) + prep(12 variants)
//   K2 gate  : gate + mi_loss + conv work-list planner (parallel)
//   K3 conv1 : worklist-driven implicit-GEMM (bias + fast GELU)
//   K4 conv2 : worklist-driven implicit-GEMM (bias)
//   K5 combine: post-transform * gate -> NCHW f32
//
// ws layout (elements):
//   wsf (f32) [0..4095]: wsi[0..7]=slot expert, wsi[8..15]=slot batch,
//                        wsf[16..23]=gate, wsf[64..575]=xp,
//                        wsi[600]=N work items, wsi[640..1151]=worklist
//   wt2 (bf16) 16*294912  all-expert weights, MFMA-frag order:
//              [e][which][k=tap*4+icc][oc16blk(0..7)][lane(0..63)][j(0..7)]
//   pbuf (bf16) 4*5376*128  prepped inputs [b][tp0:1024px|tp1:4096px|tp2:256px]
//   buf1 (bf16) 8*524288   conv1 out (per slot NHWC)
//   buf0 (bf16) 8*524288   conv2 out (per slot NHWC)
// ---------------------------------------------------------------------------

typedef __attribute__((ext_vector_type(8))) short bf16x8;
typedef __attribute__((ext_vector_type(4))) float f32x4;

#define SLOT_ELEMS 524288
#define WT_E       294912            // per expert (both convs)

__device__ inline ushort f2bf(float f) {
  unsigned u = __float_as_uint(f);
  return (ushort)((u + 0x7FFFu + ((u >> 16) & 1u)) >> 16);
}
__device__ inline float bf2f(ushort h) {
  return __uint_as_float(((unsigned)h) << 16);
}
__device__ inline float gelu_fast(float v) {      // tanh-form GELU, err<~4e-4
  float v2 = v * v;
  float z2 = v * fmaf(0.0713548162726f, v2, 1.59576912161f);
  float ex = __expf(-z2);
  return __fdividef(v, 1.0f + ex);
}

// ---------------- K1: xp + wtrans_all (LDS transpose) + prep_all ------------
__global__ __launch_bounds__(256) void front_kernel(const float* __restrict__ x,
                                                    const float* __restrict__ cw1,
                                                    const float* __restrict__ cw2,
                                                    float* __restrict__ wsf,
                                                    ushort* __restrict__ wt2,
                                                    ushort* __restrict__ pbuf) {
  int bid = blockIdx.x, tid = threadIdx.x;
  __shared__ union {
    float  red[4];                   // xp reduce
    ushort swT[1152 * 17];           // wtrans transpose: [r=ic*9+tap][oc] 39.2KB
    ushort sT[128 * 65];             // prep transpose
  } sh;

  // ---- A: xp — (b,c) = bid (blocks 0..511) ----
  if (bid < 512) {
    const float4* p = (const float4*)(x + (size_t)bid * 1024);
    float4 v = p[tid];
    float s = v.x + v.y + v.z + v.w;
    #pragma unroll
    for (int off = 32; off > 0; off >>= 1) s += __shfl_down(s, off);
    if ((tid & 63) == 0) sh.red[tid >> 6] = s;
    __syncthreads();
    if (tid == 0)
      wsf[64 + bid] = (sh.red[0] + sh.red[1] + sh.red[2] + sh.red[3]) *
                      (1.0f / 1024.0f);
    __syncthreads();                 // red dead before sh reuse
  }

  if (bid < 256) {
    // ---- B: wtrans block = (e, which, oc-block) ----
    int e = bid >> 4, which = (bid >> 3) & 1, blk = bid & 7;
    const float* src = (which ? cw2 : cw1) +
                       ((size_t)e * 128 + blk * 16) * 1152;
    // coalesced linear load of 16 oc-rows x 1152, bf16 into LDS [r][oc]
    // (write stride 17 ushorts -> conflict-free; 1152 % 64 == 0 so a wave
    //  never straddles an oc row)
    #pragma unroll 24
    for (int i = 0; i < 72; ++i) {
      int idx = i * 256 + tid;                 // oc*1152 + r
      int oc = idx / 1152, r = idx - oc * 1152;
      sh.swT[r * 17 + oc] = f2bf(src[idx]);
    }
    __syncthreads();
    // emit MFMA-frag order: 36 chunks, 4 per iter; 16B/lane coalesced stores
    ushort* dst = wt2 + ((size_t)e * 2 + which) * 147456;
    int lane = tid & 63, cq = tid >> 6;
    int ol = lane & 15, h = lane >> 4;
    #pragma unroll
    for (int it = 0; it < 9; ++it) {
      int chunk = it * 4 + cq;                 // tap*4 + icc
      int tap = chunk >> 2, icc = chunk & 3;
      bf16x8 pkv;
      #pragma unroll
      for (int j = 0; j < 8; ++j) {
        int ic = icc * 32 + h * 8 + j;
        pkv[j] = (short)sh.swT[(ic * 9 + tap) * 17 + ol];
      }
      *(bf16x8*)&dst[((size_t)(chunk * 8 + blk)) * 512 + lane * 8] = pkv;
    }
  } else {
    // ---- C: prep — chunk pc = bid-256 of 336 (12 variants x 64px chunks) ----
    int pc = bid - 256;
    if (pc < 336) {
      int b = pc / 84, r = pc - (pc / 84) * 84;
      int tp, chunk, S, pp;
      if (r < 16)      { tp = 0; chunk = r;      S = 32; pp = 0; }
      else if (r < 80) { tp = 1; chunk = r - 16; S = 64; pp = 1024; }
      else             { tp = 2; chunk = r - 80; S = 16; pp = 5120; }
      const float* xb = x + (size_t)b * 131072;
      int pxl0 = tid & 63, c0 = tid >> 6;
      #pragma unroll 4
      for (int i = 0; i < 32; ++i) {
        int c = i * 4 + c0;
        int px = chunk * 64 + pxl0;
        float v;
        if (tp == 0) {
          v = xb[c * 1024 + px];
        } else if (tp == 1) {
          int h = px >> 6, w = px & 63;
          v = xb[c * 1024 + (h >> 1) * 32 + (w >> 1)];
        } else {
          int h = px >> 4, w = px & 15;
          const float* p = xb + c * 1024 + (h << 1) * 32 + (w << 1);
          v = fmaxf(fmaxf(p[0], p[1]), fmaxf(p[32], p[33]));
        }
        sh.sT[c * 65 + pxl0] = f2bf(v);
      }
      __syncthreads();
      ushort* ob = pbuf + ((size_t)b * 5376 + pp) * 128;
      #pragma unroll
      for (int i = 0; i < 4; ++i) {
        int u = i * 256 + tid;
        int pxl = u >> 4, q = u & 15;
        bf16x8 pk;
        #pragma unroll
        for (int j = 0; j < 8; ++j) pk[j] = (short)sh.sT[(q * 8 + j) * 65 + pxl];
        *(bf16x8*)&ob[(size_t)(chunk * 64 + pxl) * 128 + q * 8] = pk;
      }
    }
  }
}

// ---------------- K2: gate + mi_loss + planner (parallel) -------------------
__global__ __launch_bounds__(256) void gate_kernel(const float* __restrict__ tf,
                                                   const float* __restrict__ Wx,
                                                   const float* __restrict__ Wt,
                                                   float* __restrict__ wsf,
                                                   float* __restrict__ out) {
  __shared__ float part[4][64];
  __shared__ float slog[64];
  __shared__ float sprob[64];
  __shared__ float ssum[4];
  __shared__ int   se[16];          // slot -> expert (post top-2)
  __shared__ int   snt[8];          // slot -> tile count
  int tid = threadIdx.x;
  int p = tid >> 6, be = tid & 63;
  int b = be >> 4, e = be & 15;
  const float* xp = wsf + 64;

  float acc = 0.0f;
  #pragma unroll 8
  for (int c = p * 32; c < p * 32 + 32; ++c)
    acc += xp[b * 128 + c] * Wx[c * 16 + e];
  {
    const float4* tf4 = (const float4*)(tf + b * 512 + p * 128);
    #pragma unroll 8
    for (int d4 = 0; d4 < 32; ++d4) {
      float4 t4 = tf4[d4];
      int d = p * 128 + d4 * 4;
      acc += t4.x * Wt[(d + 0) * 16 + e];
      acc += t4.y * Wt[(d + 1) * 16 + e];
      acc += t4.z * Wt[(d + 2) * 16 + e];
      acc += t4.w * Wt[(d + 3) * 16 + e];
    }
  }
  part[p][be] = acc;
  __syncthreads();

  if (tid < 64) slog[be] = part[0][be] + part[1][be] + part[2][be] + part[3][be];
  __syncthreads();
  if (tid < 64) {
    float m = slog[b * 16];
    for (int j = 1; j < 16; ++j) m = fmaxf(m, slog[b * 16 + j]);
    sprob[be] = expf(slog[be] - m);
  }
  __syncthreads();
  if (tid < 4) {                            // tid = b
    float s = 0.0f;
    for (int j = 0; j < 16; ++j) s += sprob[tid * 16 + j];
    ssum[tid] = s;
    int i1 = 0; float v1 = -1.0f;
    for (int j = 0; j < 16; ++j) {
      float v = sprob[tid * 16 + j];
      if (v > v1) { v1 = v; i1 = j; }
    }
    int i2 = -1; float v2 = -1.0f;
    for (int j = 0; j < 16; ++j) {
      if (j == i1) continue;
      float v = sprob[tid * 16 + j];
      if (v > v2) { v2 = v; i2 = j; }
    }
    float inv = 1.0f / (v1 + v2);           // softmax denom cancels
    int* wsi = (int*)wsf;
    wsi[2 * tid]     = i1;  wsi[2 * tid + 1]     = i2;
    wsi[8 + 2 * tid] = tid; wsi[8 + 2 * tid + 1] = tid;
    wsf[16 + 2 * tid]     = v1 * inv;
    wsf[16 + 2 * tid + 1] = v2 * inv;
    se[2 * tid] = i1; se[2 * tid + 1] = i2;
  }
  __syncthreads();
  if (tid < 8) {
    int ee = se[tid];
    int tp = ee % 3;
    snt[tid] = (tp == 0) ? 16 : ((tp == 1) ? 64 : 4);
  }
  __syncthreads();
  if (tid < 8) {                            // parallel planner: stores only
    int pre = 0;
    #pragma unroll
    for (int s = 0; s < 8; ++s) pre += (s < tid) ? snt[s] : 0;
    int ee = se[tid];
    int tp = ee % 3;
    int nt = snt[tid];
    int bb = tid >> 1;
    int ent_base = tid | (ee << 12) | (tp << 16) | (bb << 20);
    int* wl = (int*)wsf + 640;
    for (int t = 0; t < nt; ++t) wl[pre + t] = ent_base | (t << 4);
    if (tid == 7) ((int*)wsf)[600] = pre + nt;
  }
  if (tid == 32) {
    float kl = 0.0f;
    for (int j = 0; j < 16; ++j) {
      float pe = 0.25f * (sprob[j] / ssum[0] + sprob[16 + j] / ssum[1] +
                          sprob[32 + j] / ssum[2] + sprob[48 + j] / ssum[3]);
      kl += pe * logf(pe / (pe + 1e-7f) + 1e-7f);
    }
    out[524288] = -0.01f * kl;              // mi_loss
  }
}

// ---------------- K3/K4: conv3x3 via MFMA implicit GEMM ---------------------
// worklist-driven; block = 128 oc x 64 px (8x8); 4 waves x (32 oc x 64 px);
// A-frags global-streamed (3-deep), B-frags LDS double-buffered.
__global__ __launch_bounds__(256, 2) void conv_mfma(const float* __restrict__ wsf,
                                                    const ushort* __restrict__ pbuf,
                                                    ushort* __restrict__ buf1,
                                                    ushort* __restrict__ buf0,
                                                    const ushort* __restrict__ wt2,
                                                    int which,
                                                    const float* __restrict__ ball,
                                                    int gelu) {
  const int* wsi = (const int*)wsf;
  int bid = blockIdx.x;
  if (bid >= wsi[600]) return;
  int ent = wsi[640 + bid];
  int slot = ent & 7;
  int tile = (ent >> 4) & 63;
  int e    = (ent >> 12) & 15;
  int tp   = (ent >> 16) & 3;
  int b    = (ent >> 20) & 3;
  int S = (tp == 0) ? 32 : ((tp == 1) ? 64 : 16);
  int tpr = S >> 3;
  int tr = (tile / tpr) << 3;
  int tc = (tile % tpr) << 3;

  const ushort* in = which
      ? (buf1 + (size_t)slot * SLOT_ELEMS)
      : (pbuf + ((size_t)b * 5376 + (tp == 0 ? 0 : (tp == 1 ? 1024 : 5120))) * 128);
  ushort* outp = (which ? buf0 : buf1) + (size_t)slot * SLOT_ELEMS;

  __shared__ ushort sIn[100 * 136];       // [halo px][128 ch + 8 pad]
  int tid = threadIdx.x;

  for (int u = tid; u < 1600; u += 256) {
    int p = u >> 4, q = u & 15;
    int hr = p / 10, wc = p - hr * 10;
    int gh = tr + hr - 1, gw = tc + wc - 1;
    bf16x8 v = {0, 0, 0, 0, 0, 0, 0, 0};
    if (gh >= 0 && gh < S && gw >= 0 && gw < S)
      v = *(const bf16x8*)&in[(size_t)(gh * S + gw) * 128 + q * 8];
    *(bf16x8*)&sIn[p * 136 + q * 8] = v;
  }

  int wid = tid >> 6, lane = tid & 63;
  int ln = lane & 15, lg = lane >> 4;
  int ocw = wid << 5;
  const float* bias = ball + e * 128;

  // bias folded into acc init: row oc = m*16 + lg*4 + j
  f32x4 acc[2][4];
  #pragma unroll
  for (int m = 0; m < 2; ++m) {
    #pragma unroll
    for (int j = 0; j < 4; ++j) {
      float bv = bias[ocw + m * 16 + lg * 4 + j];
      #pragma unroll
      for (int n = 0; n < 4; ++n) acc[m][n][j] = bv;
    }
  }

  int pxb[4];
  #pragma unroll
  for (int n = 0; n < 4; ++n) {
    int px = n * 16 + ln;
    pxb[n] = (px >> 3) * 10 + (px & 7);
  }

  const ushort* wbase = wt2 + ((size_t)e * 2 + which) * 147456
                        + (size_t)(wid * 2) * 512 + lane * 8;

  bf16x8 abuf[3][2];
  #pragma unroll
  for (int i = 0; i < 2; ++i) {
    abuf[i][0] = *(const bf16x8*)&wbase[(size_t)i * 4096];
    abuf[i][1] = *(const bf16x8*)&wbase[(size_t)i * 4096 + 512];
  }

  __syncthreads();

  bf16x8 bcur[4], bnxt[4];
  #pragma unroll
  for (int n = 0; n < 4; ++n)                 // k=0: tap 0, icc 0
    bcur[n] = *(bf16x8*)&sIn[pxb[n] * 136 + lg * 8];

  #pragma unroll 6
  for (int kk = 0; kk < 36; ++kk) {           // k = tap*4 + icc
    if (kk + 2 < 36) {
      abuf[(kk + 2) % 3][0] = *(const bf16x8*)&wbase[(size_t)(kk + 2) * 4096];
      abuf[(kk + 2) % 3][1] = *(const bf16x8*)&wbase[(size_t)(kk + 2) * 4096 + 512];
    }
    int kn = kk + 1;
    if (kn < 36) {
      int tapn = kn >> 2, iccn = kn & 3;
      int offn = (tapn / 3) * 10 + (tapn % 3);
      #pragma unroll
      for (int n = 0; n < 4; ++n)
        bnxt[n] = *(bf16x8*)&sIn[(pxb[n] + offn) * 136 + iccn * 32 + lg * 8];
    }
    #pragma unroll
    for (int m = 0; m < 2; ++m)
      #pragma unroll
      for (int n = 0; n < 4; ++n)
        acc[m][n] = __builtin_amdgcn_mfma_f32_16x16x32_bf16(abuf[kk % 3][m], bcur[n],
                                                            acc[m][n], 0, 0, 0);
    #pragma unroll
    for (int n = 0; n < 4; ++n) bcur[n] = bnxt[n];
  }

  #pragma unroll
  for (int m = 0; m < 2; ++m) {
    int oc0 = ocw + m * 16 + lg * 4;
    #pragma unroll
    for (int n = 0; n < 4; ++n) {
      int px = n * 16 + ln;
      int gh = tr + (px >> 3), gw = tc + (px & 7);
      float v0 = acc[m][n][0];
      float v1 = acc[m][n][1];
      float v2 = acc[m][n][2];
      float v3 = acc[m][n][3];
      if (gelu) {
        v0 = gelu_fast(v0); v1 = gelu_fast(v1);
        v2 = gelu_fast(v2); v3 = gelu_fast(v3);
      }
      unsigned pk0 = (unsigned)f2bf(v0) | ((unsigned)f2bf(v1) << 16);
      unsigned pk1 = (unsigned)f2bf(v2) | ((unsigned)f2bf(v3) << 16);
      uint2 st; st.x = pk0; st.y = pk1;
      *(uint2*)&outp[(size_t)(gh * S + gw) * 128 + oc0] = st;
    }
  }
}

// ---------------- K5: combine — post * gate, NHWC bf16 -> NCHW f32 ----------
__global__ __launch_bounds__(256) void combine_kernel(const float* __restrict__ wsf,
                                                      const ushort* __restrict__ bufc,
                                                      float* __restrict__ out) {
  const int* wsi = (const int*)wsf;
  int chunk = blockIdx.x, b = blockIdx.y;   // 32 chunks x 32 px
  __shared__ float sO[32 * 129];
  int tid = threadIdx.x;

  #pragma unroll
  for (int i = 0; i < 2; ++i) {
    int u = i * 256 + tid;
    int pxl = u >> 4, q = u & 15;
    int px = chunk * 32 + pxl;
    int h = px >> 5, w = px & 31;
    float a8[8];
    #pragma unroll
    for (int j = 0; j < 8; ++j) a8[j] = 0.0f;

    for (int s = 0; s < 2; ++s) {
      int slot = 2 * b + s;
      int e = wsi[slot];
      float g = wsf[16 + slot];
      int tp = e % 3;
      const ushort* cin = bufc + (size_t)slot * SLOT_ELEMS;
      if (tp == 0) {
        bf16x8 v = *(const bf16x8*)&cin[(size_t)(h * 32 + w) * 128 + q * 8];
        #pragma unroll
        for (int j = 0; j < 8; ++j) a8[j] += g * bf2f((ushort)v[j]);
      } else if (tp == 1) {                 // maxpool from 64x64
        bf16x8 v00 = *(const bf16x8*)&cin[(size_t)((2*h) * 64 + 2*w) * 128 + q * 8];
        bf16x8 v01 = *(const bf16x8*)&cin[(size_t)((2*h) * 64 + 2*w + 1) * 128 + q * 8];
        bf16x8 v10 = *(const bf16x8*)&cin[(size_t)((2*h+1) * 64 + 2*w) * 128 + q * 8];
        bf16x8 v11 = *(const bf16x8*)&cin[(size_t)((2*h+1) * 64 + 2*w + 1) * 128 + q * 8];
        #pragma unroll
        for (int j = 0; j < 8; ++j) {
          float mv = fmaxf(fmaxf(bf2f((ushort)v00[j]), bf2f((ushort)v01[j])),
                           fmaxf(bf2f((ushort)v10[j]), bf2f((ushort)v11[j])));
          a8[j] += g * mv;
        }
      } else {                              // bilinear up from 16x16
        float sh2 = h * 0.5f - 0.25f, sw2 = w * 0.5f - 0.25f;
        float fh0 = floorf(sh2), fw0 = floorf(sw2);
        int h0 = (int)fh0, w0 = (int)fw0;
        float fh = sh2 - fh0, fw = sw2 - fw0;
        int h0c = h0 < 0 ? 0 : h0, h1c = (h0 + 1 > 15) ? 15 : h0 + 1;
        int w0c = w0 < 0 ? 0 : w0, w1c = (w0 + 1 > 15) ? 15 : w0 + 1;
        bf16x8 v00 = *(const bf16x8*)&cin[(size_t)(h0c * 16 + w0c) * 128 + q * 8];
        bf16x8 v01 = *(const bf16x8*)&cin[(size_t)(h0c * 16 + w1c) * 128 + q * 8];
        bf16x8 v10 = *(const bf16x8*)&cin[(size_t)(h1c * 16 + w0c) * 128 + q * 8];
        bf16x8 v11 = *(const bf16x8*)&cin[(size_t)(h1c * 16 + w1c) * 128 + q * 8];
        #pragma unroll
        for (int j = 0; j < 8; ++j) {
          float vv = (1.0f - fh) * ((1.0f - fw) * bf2f((ushort)v00[j]) + fw * bf2f((ushort)v01[j])) +
                     fh * ((1.0f - fw) * bf2f((ushort)v10[j]) + fw * bf2f((ushort)v11[j]));
          a8[j] += g * vv;
        }
      }
    }
    #pragma unroll
    for (int j = 0; j < 8; ++j) sO[pxl * 129 + q * 8 + j] = a8[j];
  }
  __syncthreads();
  float* ob = out + (size_t)b * 131072;
  #pragma unroll 4
  for (int i = 0; i < 16; ++i) {
    int u = i * 256 + tid;
    int c = u >> 5, pxl = u & 31;
    ob[(size_t)c * 1024 + chunk * 32 + pxl] = sO[pxl * 129 + c];
  }
}

// ---------------------------------------------------------------------------
extern "C" void kernel_launch(void* const* d_in, const int* in_sizes, int n_in,
                              void* d_out, int out_size, void* d_ws, size_t ws_size,
                              hipStream_t stream) {
  const float* x   = (const float*)d_in[0];
  const float* tf  = (const float*)d_in[1];
  const float* Wx  = (const float*)d_in[2];
  const float* Wt  = (const float*)d_in[3];
  const float* cw1 = (const float*)d_in[4];
  const float* cb1 = (const float*)d_in[5];
  const float* cw2 = (const float*)d_in[6];
  const float* cb2 = (const float*)d_in[7];
  float* out = (float*)d_out;

  float*  wsf  = (float*)d_ws;                    // 4096 f32
  ushort* wt2  = (ushort*)(wsf + 4096);           // 16*294912
  ushort* pbuf = wt2 + 16 * (size_t)WT_E;         // 4*5376*128
  ushort* buf1 = pbuf + 4 * 5376 * 128;           // 8*524288
  ushort* buf0 = buf1 + 8 * (size_t)SLOT_ELEMS;   // 8*524288

  hipLaunchKernelGGL(front_kernel,   dim3(592),    dim3(256), 0, stream, x, cw1, cw2, wsf, wt2, pbuf);
  hipLaunchKernelGGL(gate_kernel,    dim3(1),      dim3(256), 0, stream, tf, Wx, Wt, wsf, out);
  hipLaunchKernelGGL(conv_mfma,      dim3(512),    dim3(256), 0, stream, wsf, pbuf, buf1, buf0, wt2, 0, cb1, 1);
  hipLaunchKernelGGL(conv_mfma,      dim3(512),    dim3(256), 0, stream, wsf, pbuf, buf1, buf0, wt2, 1, cb2, 0);
  hipLaunchKernelGGL(combine_kernel, dim3(32, 4),  dim3(256), 0, stream, wsf, buf0, out);
}